// Round 12
// baseline (329.154 us; speedup 1.0000x reference)
//
#include <hip/hip_runtime.h>
#include <hip/hip_bf16.h>

typedef unsigned short u16;
typedef unsigned int u32;
typedef short s16x8 __attribute__((ext_vector_type(8)));
typedef float f32x4 __attribute__((ext_vector_type(4)));
typedef float f32x16 __attribute__((ext_vector_type(16)));
typedef u16 u16x4 __attribute__((ext_vector_type(4)));
typedef u32 u32x4 __attribute__((ext_vector_type(4)));

#define D_MODEL 1024
#define NHEAD 16
#define DK 64
#define B_ 4
#define N_ 2048
#define M_TOT (B_ * N_) /* 8192 */
#define QBLK 128
#define KVBLK 64
#define SCALE2 0.1803368801111137f /* 0.125 * log2(e) */

__device__ __forceinline__ u16 f2b(float x) {
  __hip_bfloat16 h = __float2bfloat16(x);
  return __builtin_bit_cast(u16, h);
}

__device__ __forceinline__ u32 cvtpk(float lo, float hi) {
  u32 r;
  asm("v_cvt_pk_bf16_f32 %0, %1, %2" : "=v"(r) : "v"(lo), "v"(hi));
  return r;
}

__device__ __forceinline__ void gload_lds16(const void* gp, void* lp) {
  __builtin_amdgcn_global_load_lds(
      (const __attribute__((address_space(1))) unsigned int*)gp,
      (__attribute__((address_space(3))) unsigned int*)lp, 16, 0, 0);
}

// ---------------- elementwise f32 -> bf16 ----------------
__global__ __launch_bounds__(256) void cvt_f32_bf16(const float* __restrict__ x,
                                                    u16* __restrict__ y, int n4) {
  int i = blockIdx.x * 256 + threadIdx.x;
  if (i < n4) {
    f32x4 v = *(const f32x4*)(x + (size_t)i * 4);
    u16x4 o;
    o[0] = f2b(v[0]); o[1] = f2b(v[1]); o[2] = f2b(v[2]); o[3] = f2b(v[3]);
    *(u16x4*)(y + (size_t)i * 4) = o;
  }
}

// ---------------- padding mask -> float bias (0 or -inf) ----------------
__global__ __launch_bounds__(256) void mask_bias(const int* __restrict__ mask,
                                                 float* __restrict__ Mb, int n) {
  int i = blockIdx.x * 256 + threadIdx.x;
  if (i < n) Mb[i] = mask[i] ? 0.f : -INFINITY;
}

// ---------------- W (f32, [K][N]) -> W^T (bf16, [N][K]) ----------------
__global__ __launch_bounds__(256) void wtrans(const float* __restrict__ W,
                                              u16* __restrict__ Wt) {
  __shared__ float tile[32][33];
  int bi = blockIdx.y, bj = blockIdx.x;
  int tx = threadIdx.x & 31, ty = threadIdx.x >> 5; // 32 x 8
#pragma unroll
  for (int r = 0; r < 4; ++r)
    tile[ty + r * 8][tx] = W[(size_t)(bi * 32 + ty + r * 8) * D_MODEL + bj * 32 + tx];
  __syncthreads();
#pragma unroll
  for (int r = 0; r < 4; ++r)
    Wt[(size_t)(bj * 32 + ty + r * 8) * D_MODEL + bi * 32 + tx] = f2b(tile[tx][ty + r * 8]);
}

// ------------- V [B,N,H*64] bf16 -> Vt [B,H,64,N] bf16 -------------
__global__ __launch_bounds__(256) void vtrans(const u16* __restrict__ Vp,
                                              u16* __restrict__ Vt) {
  __shared__ u16 tile[64][65];
  int n0 = blockIdx.x * 64, h = blockIdx.y, b = blockIdx.z;
  int tx = threadIdx.x & 63, ty = threadIdx.x >> 6;
  for (int r = ty; r < 64; r += 4)
    tile[r][tx] = Vp[(size_t)(b * N_ + n0 + r) * D_MODEL + h * DK + tx];
  __syncthreads();
  for (int r = ty; r < 64; r += 4)
    Vt[((size_t)(b * NHEAD + h) * DK + r) * N_ + n0 + tx] = tile[tx][r];
}

// ------------- GEMM: C[M,N] = A[M,K](bf16) * Bt[N,K](bf16)^T -------------
template <bool OUT_F32>
__global__ __launch_bounds__(256) void gemm_bt(const u16* __restrict__ A,
                                               const u16* __restrict__ Bt,
                                               float* __restrict__ Cf,
                                               u16* __restrict__ Cb,
                                               int M, int N, int K) {
  __shared__ __align__(16) u16 Atile[128 * 32];
  __shared__ __align__(16) u16 Btile[128 * 32];
  int tid = threadIdx.x;
  int w = tid >> 6, lane = tid & 63;
  int g = lane >> 4, c = lane & 15;
  int wr = w >> 1, wc = w & 1;
  int bi = blockIdx.y, bj = blockIdx.x;
  const int rowA0 = bi * 128, rowB0 = bj * 128;

  const f32x4 fzero = {0.f, 0.f, 0.f, 0.f};
  f32x4 acc[4][4];
#pragma unroll
  for (int m = 0; m < 4; ++m)
#pragma unroll
    for (int n = 0; n < 4; ++n) acc[m][n] = fzero;

  for (int k0 = 0; k0 < K; k0 += 32) {
#pragma unroll
    for (int cc = 0; cc < 2; ++cc) {
      int li = w * 2 + cc;
      const u16* ga = A + (size_t)(rowA0 + li * 16 + (lane >> 2)) * K + k0 + (lane & 3) * 8;
      gload_lds16(ga, &Atile[li * 512]);
      const u16* gb = Bt + (size_t)(rowB0 + li * 16 + (lane >> 2)) * K + k0 + (lane & 3) * 8;
      gload_lds16(gb, &Btile[li * 512]);
    }
    __syncthreads();
    s16x8 af[4], bfr[4];
#pragma unroll
    for (int m = 0; m < 4; ++m)
      af[m] = *(const s16x8*)&Atile[(wr * 64 + m * 16 + c) * 32 + g * 8];
#pragma unroll
    for (int n = 0; n < 4; ++n)
      bfr[n] = *(const s16x8*)&Btile[(wc * 64 + n * 16 + c) * 32 + g * 8];
#pragma unroll
    for (int m = 0; m < 4; ++m)
#pragma unroll
      for (int n = 0; n < 4; ++n)
        acc[m][n] = __builtin_amdgcn_mfma_f32_16x16x32_bf16(af[m], bfr[n], acc[m][n], 0, 0, 0);
    __syncthreads();
  }
#pragma unroll
  for (int m = 0; m < 4; ++m)
#pragma unroll
    for (int n = 0; n < 4; ++n)
#pragma unroll
      for (int r = 0; r < 4; ++r) {
        int row = rowA0 + wr * 64 + m * 16 + g * 4 + r;
        int col = rowB0 + wc * 64 + n * 16 + c;
        size_t idx = (size_t)row * N + col;
        if (OUT_F32) Cf[idx] = acc[m][n][r];
        else Cb[idx] = f2b(acc[m][n][r]);
      }
}

#define MAX4(a, b, c, d) fmaxf(fmaxf(a, b), fmaxf(c, d))

// ------------- causal flash attention: 32x32 MFMA + in-register softmax ---
// Swapped QK^T (mfma(K,Q) -> S^T): lane owns q=lane&31, 32 kv values in regs
// (kv = (r&3)+8*(r>>2)+4*hi). Softmax fully in-register; P -> PV A-operand
// via cvt_pk + permlane32_swap (T12). Zero LDS, no barriers. XCD-local
// heads, paired q-tiles {15-p,p}, K reg dbuf prefetch, V at tile top,
// defer-max (T13), reg-direct L2 loads.
__global__ __launch_bounds__(256) void attn_fwd(const u16* __restrict__ Qp,
                                                const u16* __restrict__ Kp,
                                                const u16* __restrict__ Vt,
                                                const float* __restrict__ Mb,
                                                u16* __restrict__ Out) {
  int bid = blockIdx.x;
  int xcd = bid & 7;
  int inner = bid >> 3; // 0..63
  int j = inner >> 3;   // head-within-XCD 0..7
  int pair = inner & 7; // 0..7
  int bh = xcd * 8 + j; // 0..63
  int b = bh >> 4, h = bh & 15;
  int tid = threadIdx.x, w = tid >> 6, lane = tid & 63;
  int q32 = lane & 31, hi = lane >> 5;
  int hi8 = hi * 8, hi4 = hi * 4;

  const u16* kbase = Kp + (size_t)b * N_ * D_MODEL + h * DK;
  const u16* vbase = Vt + (size_t)(b * NHEAD + h) * DK * N_;
  const float* mp0 = Mb + (size_t)b * N_;

  const f32x16 fz16 = {0.f, 0.f, 0.f, 0.f, 0.f, 0.f, 0.f, 0.f,
                       0.f, 0.f, 0.f, 0.f, 0.f, 0.f, 0.f, 0.f};

#pragma unroll 1
  for (int ph = 0; ph < 2; ++ph) {
    int qt = ph ? pair : 15 - pair;
    int q0 = qt * QBLK;
    int wq0 = q0 + w * 32; // this wave's first q row
    int ntw = wq0 / KVBLK + 1;
    int qq = wq0 + q32;

    // Q (B-operand): lane holds Q[wq0+q32][kk*16+hi*8+e]
    s16x8 qf[4];
    {
      const u16* qb2 = Qp + (size_t)(b * N_ + wq0 + q32) * D_MODEL + h * DK;
#pragma unroll
      for (int kk = 0; kk < 4; ++kk) qf[kk] = *(const s16x8*)(qb2 + kk * 16 + hi8);
    }

    f32x16 oacc[2];
    oacc[0] = fz16; oacc[1] = fz16;
    float mr = -1e30f, lr = 0.f; // per-lane (q=q32); lr = half-row partial

    auto loadk = [&](s16x8(&kf)[2][4], int t) {
      int kv0 = t * KVBLK;
#pragma unroll
      for (int n = 0; n < 2; ++n)
#pragma unroll
        for (int kk = 0; kk < 4; ++kk)
          kf[n][kk] = *(const s16x8*)&kbase[(size_t)(kv0 + n * 32 + q32) * D_MODEL + kk * 16 + hi8];
    };

    auto step = [&](s16x8(&kc)[2][4], s16x8(&kn)[2][4], int t) {
      int kv0 = t * KVBLK;
      if (t + 1 < ntw) loadk(kn, t + 1); // prefetch next K tile (other bank)
      // V (B-operand) for THIS tile, issued early
      s16x8 vf[2][2][2];
#pragma unroll
      for (int n = 0; n < 2; ++n)
#pragma unroll
        for (int kk2 = 0; kk2 < 2; ++kk2)
#pragma unroll
          for (int d0 = 0; d0 < 2; ++d0)
            vf[n][kk2][d0] = *(const s16x8*)&vbase[(size_t)(d0 * 32 + q32) * N_ +
                                                   kv0 + n * 32 + kk2 * 16 + hi8];
      f32x4 mbv[2][4];
#pragma unroll
      for (int n = 0; n < 2; ++n)
#pragma unroll
        for (int jj = 0; jj < 4; ++jj)
          mbv[n][jj] = *(const f32x4*)&mp0[kv0 + n * 32 + jj * 8 + hi4];

      // ---- S^T = K Q^T : st[n][r] = S[q=wq0+q32][kv=kv0+n*32+(r&3)+8*(r>>2)+4hi]
      f32x16 st[2];
#pragma unroll
      for (int n = 0; n < 2; ++n) {
        f32x16 a = fz16;
        a = __builtin_amdgcn_mfma_f32_32x32x16_bf16(kc[n][0], qf[0], a, 0, 0, 0);
        a = __builtin_amdgcn_mfma_f32_32x32x16_bf16(kc[n][1], qf[1], a, 0, 0, 0);
        a = __builtin_amdgcn_mfma_f32_32x32x16_bf16(kc[n][2], qf[2], a, 0, 0, 0);
        a = __builtin_amdgcn_mfma_f32_32x32x16_bf16(kc[n][3], qf[3], a, 0, 0, 0);
        st[n] = a;
      }

      // ---- scale + padding bias + causal mask
      bool diag = (kv0 + KVBLK - 1 > wq0);
#pragma unroll
      for (int n = 0; n < 2; ++n)
#pragma unroll
        for (int r = 0; r < 16; ++r) {
          float v = fmaf(st[n][r], SCALE2, mbv[n][r >> 2][r & 3]);
          if (diag) {
            int kv = kv0 + n * 32 + (r & 3) + 8 * (r >> 2) + hi4;
            v = (kv > qq) ? -INFINITY : v;
          }
          st[n][r] = v;
        }
      // per-lane max over its 32 values (tree)
      float a0 = MAX4(st[0][0], st[0][1], st[0][2], st[0][3]);
      float a1 = MAX4(st[0][4], st[0][5], st[0][6], st[0][7]);
      float a2 = MAX4(st[0][8], st[0][9], st[0][10], st[0][11]);
      float a3 = MAX4(st[0][12], st[0][13], st[0][14], st[0][15]);
      float b0 = MAX4(st[1][0], st[1][1], st[1][2], st[1][3]);
      float b1 = MAX4(st[1][4], st[1][5], st[1][6], st[1][7]);
      float b2 = MAX4(st[1][8], st[1][9], st[1][10], st[1][11]);
      float b3 = MAX4(st[1][12], st[1][13], st[1][14], st[1][15]);
      float pmax = fmaxf(MAX4(a0, a1, a2, a3), MAX4(b0, b1, b2, b3));

      // ---- defer-max rescale (T13); al identical for lane pair (q, q+32)
      if (__any(pmax > mr + 8.f)) {
        float pm2 = fmaxf(pmax, __shfl_xor(pmax, 32));
        float mnew = fmaxf(mr, pm2);
        float al = exp2f(mr - mnew);
        mr = mnew;
        lr *= al;
#pragma unroll
        for (int r = 0; r < 16; ++r) {
          float alT = __shfl(al, (r & 3) + 8 * (r >> 2) + hi4);
          oacc[0][r] *= alT;
          oacc[1][r] *= alT;
        }
      }

      // ---- p = exp2(s - m) (lane-local sum), pack -> PV A-frags (T12)
      s16x8 pa[2][2];
#pragma unroll
      for (int n = 0; n < 2; ++n) {
#pragma unroll
        for (int r = 0; r < 16; ++r) st[n][r] = exp2f(st[n][r] - mr);
        float s01 = st[n][0] + st[n][1], s23 = st[n][2] + st[n][3];
        float s45 = st[n][4] + st[n][5], s67 = st[n][6] + st[n][7];
        float s89 = st[n][8] + st[n][9], sab = st[n][10] + st[n][11];
        float scd = st[n][12] + st[n][13], sef = st[n][14] + st[n][15];
        lr += ((s01 + s23) + (s45 + s67)) + ((s89 + sab) + (scd + sef));
        u32 x0 = cvtpk(st[n][0], st[n][1]);
        u32 x1 = cvtpk(st[n][2], st[n][3]);
        u32 x2 = cvtpk(st[n][4], st[n][5]);
        u32 x3 = cvtpk(st[n][6], st[n][7]);
        auto sA = __builtin_amdgcn_permlane32_swap(x0, x2, false, false);
        auto sB = __builtin_amdgcn_permlane32_swap(x1, x3, false, false);
        u32x4 w0 = {sA[0], sB[0], sA[1], sB[1]};
        pa[n][0] = __builtin_bit_cast(s16x8, w0);
        u32 x4 = cvtpk(st[n][8], st[n][9]);
        u32 x5 = cvtpk(st[n][10], st[n][11]);
        u32 x6 = cvtpk(st[n][12], st[n][13]);
        u32 x7 = cvtpk(st[n][14], st[n][15]);
        auto sC = __builtin_amdgcn_permlane32_swap(x4, x6, false, false);
        auto sD = __builtin_amdgcn_permlane32_swap(x5, x7, false, false);
        u32x4 w1 = {sC[0], sD[0], sC[1], sD[1]};
        pa[n][1] = __builtin_bit_cast(s16x8, w1);
      }

      // ---- O += P * V (in-register A-operand)
#pragma unroll
      for (int n = 0; n < 2; ++n)
#pragma unroll
        for (int kk2 = 0; kk2 < 2; ++kk2)
#pragma unroll
          for (int d0 = 0; d0 < 2; ++d0)
            oacc[d0] = __builtin_amdgcn_mfma_f32_32x32x16_bf16(pa[n][kk2], vf[n][kk2][d0], oacc[d0], 0, 0, 0);
    };

    s16x8 kA[2][4], kB[2][4];
    loadk(kA, 0);
    for (int t = 0; t < ntw; t += 2) {
      step(kA, kB, t);
      if (t + 1 < ntw) step(kB, kA, t + 1);
    }

    // ---- epilogue: complete l across lane pair, normalize + store
    lr += __shfl_xor(lr, 32);
#pragma unroll
    for (int r = 0; r < 16; ++r) {
      int qoff = (r & 3) + 8 * (r >> 2) + hi4;
      float lq = __shfl(lr, qoff);
      float inv = lq > 0.f ? 1.f / lq : 0.f;
      size_t base = (size_t)(b * N_ + wq0 + qoff) * D_MODEL + h * DK + q32;
      Out[base] = f2b(oacc[0][r] * inv);
      Out[base + 32] = f2b(oacc[1][r] * inv);
    }
  }
}

extern "C" void kernel_launch(void* const* d_in, const int* in_sizes, int n_in,
                              void* d_out, int out_size, void* d_ws, size_t ws_size,
                              hipStream_t stream) {
  const float* q = (const float*)d_in[0];
  const float* k = (const float*)d_in[1];
  const float* v = (const float*)d_in[2];
  const int* mask = (const int*)d_in[3];
  const float* Wq = (const float*)d_in[4];
  const float* Wk = (const float*)d_in[5];
  const float* Wv = (const float*)d_in[6];
  const float* Wo = (const float*)d_in[7];
  float* out = (float*)d_out;

  char* ws = (char*)d_ws;
  const size_t SZ = (size_t)M_TOT * D_MODEL * 2; // 16 MiB per bf16 [8192,1024]
  u16* qb = (u16*)ws;
  u16* kb = (u16*)(ws + SZ);
  u16* vb = (u16*)(ws + 2 * SZ);
  u16* Qp = (u16*)(ws + 3 * SZ);
  u16* Kp = (u16*)(ws + 4 * SZ);
  u16* Wqt = (u16*)(ws + 5 * SZ);
  u16* Wkt = Wqt + 1024 * 1024;
  u16* Wvt = Wkt + 1024 * 1024;
  u16* Wot = Wvt + 1024 * 1024;
  float* Mb = (float*)(Wot + 1024 * 1024);
  // aliases (lifetime-disjoint):
  u16* attn_out = qb; // qb dead after Q GEMM
  u16* Vp = kb;       // kb dead after K GEMM
  u16* Vt = vb;       // vb dead after V GEMM

  int n4 = M_TOT * D_MODEL / 4;
  cvt_f32_bf16<<<n4 / 256, 256, 0, stream>>>(q, qb, n4);
  cvt_f32_bf16<<<n4 / 256, 256, 0, stream>>>(k, kb, n4);
  cvt_f32_bf16<<<n4 / 256, 256, 0, stream>>>(v, vb, n4);
  mask_bias<<<(B_ * N_ + 255) / 256, 256, 0, stream>>>(mask, Mb, B_ * N_);
  dim3 wg(32, 32);
  wtrans<<<wg, 256, 0, stream>>>(Wq, Wqt);
  wtrans<<<wg, 256, 0, stream>>>(Wk, Wkt);
  wtrans<<<wg, 256, 0, stream>>>(Wv, Wvt);
  wtrans<<<wg, 256, 0, stream>>>(Wo, Wot);
  dim3 gg(D_MODEL / 128, M_TOT / 128);
  gemm_bt<false><<<gg, 256, 0, stream>>>(qb, Wqt, nullptr, Qp, M_TOT, D_MODEL, D_MODEL);
  gemm_bt<false><<<gg, 256, 0, stream>>>(kb, Wkt, nullptr, Kp, M_TOT, D_MODEL, D_MODEL);
  gemm_bt<false><<<gg, 256, 0, stream>>>(vb, Wvt, nullptr, Vp, M_TOT, D_MODEL, D_MODEL);
  vtrans<<<dim3(N_ / 64, NHEAD, B_), 256, 0, stream>>>(Vp, Vt);
  attn_fwd<<<512, 256, 0, stream>>>(Qp, Kp, Vt, Mb, attn_out);
  gemm_bt<true><<<gg, 256, 0, stream>>>(attn_out, Wot, out, nullptr, M_TOT, D_MODEL, D_MODEL);
}

// Round 13
// 310.942 us; speedup vs baseline: 1.0586x; 1.0586x over previous
//
#include <hip/hip_runtime.h>
#include <hip/hip_bf16.h>

typedef unsigned short u16;
typedef unsigned int u32;
typedef short s16x8 __attribute__((ext_vector_type(8)));
typedef float f32x4 __attribute__((ext_vector_type(4)));
typedef float f32x16 __attribute__((ext_vector_type(16)));
typedef u16 u16x4 __attribute__((ext_vector_type(4)));
typedef u32 u32x4 __attribute__((ext_vector_type(4)));

#define D_MODEL 1024
#define NHEAD 16
#define DK 64
#define B_ 4
#define N_ 2048
#define M_TOT (B_ * N_) /* 8192 */
#define QBLK 128
#define KVBLK 64
#define SCALE2 0.1803368801111137f /* 0.125 * log2(e) */
#define FRAG_PER_BH 131072 /* 64 heads-worth: N_*DK elems per (b,h) */

__device__ __forceinline__ u16 f2b(float x) {
  __hip_bfloat16 h = __float2bfloat16(x);
  return __builtin_bit_cast(u16, h);
}

__device__ __forceinline__ u32 cvtpk(float lo, float hi) {
  u32 r;
  asm("v_cvt_pk_bf16_f32 %0, %1, %2" : "=v"(r) : "v"(lo), "v"(hi));
  return r;
}

__device__ __forceinline__ void gload_lds16(const void* gp, void* lp) {
  __builtin_amdgcn_global_load_lds(
      (const __attribute__((address_space(1))) unsigned int*)gp,
      (__attribute__((address_space(3))) unsigned int*)lp, 16, 0, 0);
}

// ---------------- elementwise f32 -> bf16 ----------------
__global__ __launch_bounds__(256) void cvt_f32_bf16(const float* __restrict__ x,
                                                    u16* __restrict__ y, int n4) {
  int i = blockIdx.x * 256 + threadIdx.x;
  if (i < n4) {
    f32x4 v = *(const f32x4*)(x + (size_t)i * 4);
    u16x4 o;
    o[0] = f2b(v[0]); o[1] = f2b(v[1]); o[2] = f2b(v[2]); o[3] = f2b(v[3]);
    *(u16x4*)(y + (size_t)i * 4) = o;
  }
}

// ---------------- padding mask -> float bias (0 or -inf) ----------------
__global__ __launch_bounds__(256) void mask_bias(const int* __restrict__ mask,
                                                 float* __restrict__ Mb, int n) {
  int i = blockIdx.x * 256 + threadIdx.x;
  if (i < n) Mb[i] = mask[i] ? 0.f : -INFINITY;
}

// ---------------- W (f32, [K][N]) -> W^T (bf16, [N][K]) ----------------
__global__ __launch_bounds__(256) void wtrans(const float* __restrict__ W,
                                              u16* __restrict__ Wt) {
  __shared__ float tile[32][33];
  int bi = blockIdx.y, bj = blockIdx.x;
  int tx = threadIdx.x & 31, ty = threadIdx.x >> 5; // 32 x 8
#pragma unroll
  for (int r = 0; r < 4; ++r)
    tile[ty + r * 8][tx] = W[(size_t)(bi * 32 + ty + r * 8) * D_MODEL + bj * 32 + tx];
  __syncthreads();
#pragma unroll
  for (int r = 0; r < 4; ++r)
    Wt[(size_t)(bj * 32 + ty + r * 8) * D_MODEL + bi * 32 + tx] = f2b(tile[tx][ty + r * 8]);
}

// ------------- K [B,N,H*64] -> fragment-major Kf -------------
// Frag (b,h,kv32,kk): elem (lane,e) = K[b][kv32*32+(lane&31)][h*64+kk*16+(lane>>5)*8+e]
// stored at (b*16+h)*FRAG_PER_BH + ((kv32*4)+kk)*512 + lane*8 + e  (1KB contiguous)
__global__ __launch_bounds__(256) void kfrag_k(const u16* __restrict__ Kp,
                                               u16* __restrict__ Kf) {
  __shared__ __align__(16) u16 tile[64][72];
  int kv0 = blockIdx.x * 64, h = blockIdx.y, b = blockIdx.z;
  int tid = threadIdx.x;
#pragma unroll
  for (int it = 0; it < 2; ++it) {
    int r = it * 32 + (tid >> 3), c8 = (tid & 7) * 8;
    *(s16x8*)&tile[r][c8] =
        *(const s16x8*)&Kp[(size_t)(b * N_ + kv0 + r) * D_MODEL + h * DK + c8];
  }
  __syncthreads();
  int w = tid >> 6, lane = tid & 63;
  int q32 = lane & 31, hi = lane >> 5;
  size_t kfb = (size_t)(b * NHEAD + h) * FRAG_PER_BH;
#pragma unroll
  for (int kv32L = 0; kv32L < 2; ++kv32L) {
    s16x8 v = *(const s16x8*)&tile[kv32L * 32 + q32][w * 16 + hi * 8];
    *(s16x8*)&Kf[kfb + ((size_t)(kv0 / 32 + kv32L) * 4 + w) * 512 + lane * 8] = v;
  }
}

// ------------- V [B,N,H*64] -> fragment-major Vf -------------
// Frag (b,h,kv16,d0): elem (lane,e) = V[b][kv16*16+(lane>>5)*8+e][h*64+d0*32+(lane&31)]
// stored at (b*16+h)*FRAG_PER_BH + ((kv16*2)+d0)*512 + lane*8 + e
__global__ __launch_bounds__(256) void vfrag_k(const u16* __restrict__ Vp,
                                               u16* __restrict__ Vf) {
  __shared__ __align__(16) u16 tile[64][72];
  int n0 = blockIdx.x * 64, h = blockIdx.y, b = blockIdx.z;
  int tid = threadIdx.x;
#pragma unroll
  for (int it = 0; it < 2; ++it) {
    int r = it * 32 + (tid >> 3), c8 = (tid & 7) * 8;
    *(s16x8*)&tile[r][c8] =
        *(const s16x8*)&Vp[(size_t)(b * N_ + n0 + r) * D_MODEL + h * DK + c8];
  }
  __syncthreads();
  int w = tid >> 6, lane = tid & 63; // w = local kv16 index
  int d32 = lane & 31, hi = lane >> 5;
  size_t vfb = (size_t)(b * NHEAD + h) * FRAG_PER_BH;
#pragma unroll
  for (int d0 = 0; d0 < 2; ++d0) {
    s16x8 vv;
#pragma unroll
    for (int e = 0; e < 8; ++e)
      vv[e] = (short)tile[w * 16 + hi * 8 + e][d0 * 32 + d32];
    *(s16x8*)&Vf[vfb + ((size_t)(n0 / 16 + w) * 2 + d0) * 512 + lane * 8] = vv;
  }
}

// ------------- GEMM: C[M,N] = A[M,K](bf16) * Bt[N,K](bf16)^T -------------
template <bool OUT_F32>
__global__ __launch_bounds__(256) void gemm_bt(const u16* __restrict__ A,
                                               const u16* __restrict__ Bt,
                                               float* __restrict__ Cf,
                                               u16* __restrict__ Cb,
                                               int M, int N, int K) {
  __shared__ __align__(16) u16 Atile[128 * 32];
  __shared__ __align__(16) u16 Btile[128 * 32];
  int tid = threadIdx.x;
  int w = tid >> 6, lane = tid & 63;
  int g = lane >> 4, c = lane & 15;
  int wr = w >> 1, wc = w & 1;
  int bi = blockIdx.y, bj = blockIdx.x;
  const int rowA0 = bi * 128, rowB0 = bj * 128;

  const f32x4 fzero = {0.f, 0.f, 0.f, 0.f};
  f32x4 acc[4][4];
#pragma unroll
  for (int m = 0; m < 4; ++m)
#pragma unroll
    for (int n = 0; n < 4; ++n) acc[m][n] = fzero;

  for (int k0 = 0; k0 < K; k0 += 32) {
#pragma unroll
    for (int cc = 0; cc < 2; ++cc) {
      int li = w * 2 + cc;
      const u16* ga = A + (size_t)(rowA0 + li * 16 + (lane >> 2)) * K + k0 + (lane & 3) * 8;
      gload_lds16(ga, &Atile[li * 512]);
      const u16* gb = Bt + (size_t)(rowB0 + li * 16 + (lane >> 2)) * K + k0 + (lane & 3) * 8;
      gload_lds16(gb, &Btile[li * 512]);
    }
    __syncthreads();
    s16x8 af[4], bfr[4];
#pragma unroll
    for (int m = 0; m < 4; ++m)
      af[m] = *(const s16x8*)&Atile[(wr * 64 + m * 16 + c) * 32 + g * 8];
#pragma unroll
    for (int n = 0; n < 4; ++n)
      bfr[n] = *(const s16x8*)&Btile[(wc * 64 + n * 16 + c) * 32 + g * 8];
#pragma unroll
    for (int m = 0; m < 4; ++m)
#pragma unroll
      for (int n = 0; n < 4; ++n)
        acc[m][n] = __builtin_amdgcn_mfma_f32_16x16x32_bf16(af[m], bfr[n], acc[m][n], 0, 0, 0);
    __syncthreads();
  }
#pragma unroll
  for (int m = 0; m < 4; ++m)
#pragma unroll
    for (int n = 0; n < 4; ++n)
#pragma unroll
      for (int r = 0; r < 4; ++r) {
        int row = rowA0 + wr * 64 + m * 16 + g * 4 + r;
        int col = rowB0 + wc * 64 + n * 16 + c;
        size_t idx = (size_t)row * N + col;
        if (OUT_F32) Cf[idx] = acc[m][n][r];
        else Cb[idx] = f2b(acc[m][n][r]);
      }
}

#define MAX4(a, b, c, d) fmaxf(fmaxf(a, b), fmaxf(c, d))

// ------------- causal flash attention: 32x32 MFMA, fragment-major K/V -----
// Identical structure to R12 (swapped QK^T, in-register softmax via
// cvt_pk+permlane32_swap, defer-max, zero LDS, no barriers, XCD-local heads,
// paired q-tiles, K reg dbuf prefetch) -- only the K/V load addresses
// changed to the pre-tiled fragment-major layout (coalesced, 8 trans/instr).
__global__ __launch_bounds__(256) void attn_fwd(const u16* __restrict__ Qp,
                                                const u16* __restrict__ Kf,
                                                const u16* __restrict__ Vf,
                                                const float* __restrict__ Mb,
                                                u16* __restrict__ Out) {
  int bid = blockIdx.x;
  int xcd = bid & 7;
  int inner = bid >> 3; // 0..63
  int j = inner >> 3;   // head-within-XCD 0..7
  int pair = inner & 7; // 0..7
  int bh = xcd * 8 + j; // 0..63
  int b = bh >> 4, h = bh & 15;
  int tid = threadIdx.x, w = tid >> 6, lane = tid & 63;
  int q32 = lane & 31, hi = lane >> 5;
  int hi8 = hi * 8, hi4 = hi * 4;

  const u16* kfb = Kf + (size_t)(b * NHEAD + h) * FRAG_PER_BH;
  const u16* vfb = Vf + (size_t)(b * NHEAD + h) * FRAG_PER_BH;
  const float* mp0 = Mb + (size_t)b * N_;

  const f32x16 fz16 = {0.f, 0.f, 0.f, 0.f, 0.f, 0.f, 0.f, 0.f,
                       0.f, 0.f, 0.f, 0.f, 0.f, 0.f, 0.f, 0.f};

#pragma unroll 1
  for (int ph = 0; ph < 2; ++ph) {
    int qt = ph ? pair : 15 - pair;
    int q0 = qt * QBLK;
    int wq0 = q0 + w * 32; // this wave's first q row
    int ntw = wq0 / KVBLK + 1;
    int qq = wq0 + q32;

    // Q (B-operand): lane holds Q[wq0+q32][kk*16+hi*8+e]
    s16x8 qf[4];
    {
      const u16* qb2 = Qp + (size_t)(b * N_ + wq0 + q32) * D_MODEL + h * DK;
#pragma unroll
      for (int kk = 0; kk < 4; ++kk) qf[kk] = *(const s16x8*)(qb2 + kk * 16 + hi8);
    }

    f32x16 oacc[2];
    oacc[0] = fz16; oacc[1] = fz16;
    float mr = -1e30f, lr = 0.f; // per-lane (q=q32); lr = half-row partial

    auto loadk = [&](s16x8(&kf)[2][4], int t) {
      int kv32 = t * 2;
#pragma unroll
      for (int n = 0; n < 2; ++n)
#pragma unroll
        for (int kk = 0; kk < 4; ++kk)
          kf[n][kk] = *(const s16x8*)&kfb[((size_t)(kv32 + n) * 4 + kk) * 512 + lane * 8];
    };

    auto step = [&](s16x8(&kc)[2][4], s16x8(&kn)[2][4], int t) {
      int kv0 = t * KVBLK;
      if (t + 1 < ntw) loadk(kn, t + 1); // prefetch next K tile (other bank)
      // V (B-operand) for THIS tile, issued early (fragment-major)
      int kv16 = t * 4;
      s16x8 vf[2][2][2];
#pragma unroll
      for (int n = 0; n < 2; ++n)
#pragma unroll
        for (int kk2 = 0; kk2 < 2; ++kk2)
#pragma unroll
          for (int d0 = 0; d0 < 2; ++d0)
            vf[n][kk2][d0] = *(const s16x8*)&vfb[((size_t)(kv16 + n * 2 + kk2) * 2 + d0) * 512 + lane * 8];
      f32x4 mbv[2][4];
#pragma unroll
      for (int n = 0; n < 2; ++n)
#pragma unroll
        for (int jj = 0; jj < 4; ++jj)
          mbv[n][jj] = *(const f32x4*)&mp0[kv0 + n * 32 + jj * 8 + hi4];

      // ---- S^T = K Q^T : st[n][r] = S[q=wq0+q32][kv=kv0+n*32+(r&3)+8*(r>>2)+4hi]
      f32x16 st[2];
#pragma unroll
      for (int n = 0; n < 2; ++n) {
        f32x16 a = fz16;
        a = __builtin_amdgcn_mfma_f32_32x32x16_bf16(kc[n][0], qf[0], a, 0, 0, 0);
        a = __builtin_amdgcn_mfma_f32_32x32x16_bf16(kc[n][1], qf[1], a, 0, 0, 0);
        a = __builtin_amdgcn_mfma_f32_32x32x16_bf16(kc[n][2], qf[2], a, 0, 0, 0);
        a = __builtin_amdgcn_mfma_f32_32x32x16_bf16(kc[n][3], qf[3], a, 0, 0, 0);
        st[n] = a;
      }

      // ---- scale + padding bias + causal mask
      bool diag = (kv0 + KVBLK - 1 > wq0);
#pragma unroll
      for (int n = 0; n < 2; ++n)
#pragma unroll
        for (int r = 0; r < 16; ++r) {
          float v = fmaf(st[n][r], SCALE2, mbv[n][r >> 2][r & 3]);
          if (diag) {
            int kv = kv0 + n * 32 + (r & 3) + 8 * (r >> 2) + hi4;
            v = (kv > qq) ? -INFINITY : v;
          }
          st[n][r] = v;
        }
      // per-lane max over its 32 values (tree)
      float a0 = MAX4(st[0][0], st[0][1], st[0][2], st[0][3]);
      float a1 = MAX4(st[0][4], st[0][5], st[0][6], st[0][7]);
      float a2 = MAX4(st[0][8], st[0][9], st[0][10], st[0][11]);
      float a3 = MAX4(st[0][12], st[0][13], st[0][14], st[0][15]);
      float b0 = MAX4(st[1][0], st[1][1], st[1][2], st[1][3]);
      float b1 = MAX4(st[1][4], st[1][5], st[1][6], st[1][7]);
      float b2 = MAX4(st[1][8], st[1][9], st[1][10], st[1][11]);
      float b3 = MAX4(st[1][12], st[1][13], st[1][14], st[1][15]);
      float pmax = fmaxf(MAX4(a0, a1, a2, a3), MAX4(b0, b1, b2, b3));

      // ---- defer-max rescale (T13); al identical for lane pair (q, q+32)
      if (__any(pmax > mr + 8.f)) {
        float pm2 = fmaxf(pmax, __shfl_xor(pmax, 32));
        float mnew = fmaxf(mr, pm2);
        float al = exp2f(mr - mnew);
        mr = mnew;
        lr *= al;
#pragma unroll
        for (int r = 0; r < 16; ++r) {
          float alT = __shfl(al, (r & 3) + 8 * (r >> 2) + hi4);
          oacc[0][r] *= alT;
          oacc[1][r] *= alT;
        }
      }

      // ---- p = exp2(s - m) (lane-local sum), pack -> PV A-frags (T12)
      s16x8 pa[2][2];
#pragma unroll
      for (int n = 0; n < 2; ++n) {
#pragma unroll
        for (int r = 0; r < 16; ++r) st[n][r] = exp2f(st[n][r] - mr);
        float s01 = st[n][0] + st[n][1], s23 = st[n][2] + st[n][3];
        float s45 = st[n][4] + st[n][5], s67 = st[n][6] + st[n][7];
        float s89 = st[n][8] + st[n][9], sab = st[n][10] + st[n][11];
        float scd = st[n][12] + st[n][13], sef = st[n][14] + st[n][15];
        lr += ((s01 + s23) + (s45 + s67)) + ((s89 + sab) + (scd + sef));
        u32 x0 = cvtpk(st[n][0], st[n][1]);
        u32 x1 = cvtpk(st[n][2], st[n][3]);
        u32 x2 = cvtpk(st[n][4], st[n][5]);
        u32 x3 = cvtpk(st[n][6], st[n][7]);
        auto sA = __builtin_amdgcn_permlane32_swap(x0, x2, false, false);
        auto sB = __builtin_amdgcn_permlane32_swap(x1, x3, false, false);
        u32x4 w0 = {sA[0], sB[0], sA[1], sB[1]};
        pa[n][0] = __builtin_bit_cast(s16x8, w0);
        u32 x4 = cvtpk(st[n][8], st[n][9]);
        u32 x5 = cvtpk(st[n][10], st[n][11]);
        u32 x6 = cvtpk(st[n][12], st[n][13]);
        u32 x7 = cvtpk(st[n][14], st[n][15]);
        auto sC = __builtin_amdgcn_permlane32_swap(x4, x6, false, false);
        auto sD = __builtin_amdgcn_permlane32_swap(x5, x7, false, false);
        u32x4 w1 = {sC[0], sD[0], sC[1], sD[1]};
        pa[n][1] = __builtin_bit_cast(s16x8, w1);
      }

      // ---- O += P * V (in-register A-operand)
#pragma unroll
      for (int n = 0; n < 2; ++n)
#pragma unroll
        for (int kk2 = 0; kk2 < 2; ++kk2)
#pragma unroll
          for (int d0 = 0; d0 < 2; ++d0)
            oacc[d0] = __builtin_amdgcn_mfma_f32_32x32x16_bf16(pa[n][kk2], vf[n][kk2][d0], oacc[d0], 0, 0, 0);
    };

    s16x8 kA[2][4], kB[2][4];
    loadk(kA, 0);
    for (int t = 0; t < ntw; t += 2) {
      step(kA, kB, t);
      if (t + 1 < ntw) step(kB, kA, t + 1);
    }

    // ---- epilogue: complete l across lane pair, normalize + store
    lr += __shfl_xor(lr, 32);
#pragma unroll
    for (int r = 0; r < 16; ++r) {
      int qoff = (r & 3) + 8 * (r >> 2) + hi4;
      float lq = __shfl(lr, qoff);
      float inv = lq > 0.f ? 1.f / lq : 0.f;
      size_t base = (size_t)(b * N_ + wq0 + qoff) * D_MODEL + h * DK + q32;
      Out[base] = f2b(oacc[0][r] * inv);
      Out[base + 32] = f2b(oacc[1][r] * inv);
    }
  }
}

extern "C" void kernel_launch(void* const* d_in, const int* in_sizes, int n_in,
                              void* d_out, int out_size, void* d_ws, size_t ws_size,
                              hipStream_t stream) {
  const float* q = (const float*)d_in[0];
  const float* k = (const float*)d_in[1];
  const float* v = (const float*)d_in[2];
  const int* mask = (const int*)d_in[3];
  const float* Wq = (const float*)d_in[4];
  const float* Wk = (const float*)d_in[5];
  const float* Wv = (const float*)d_in[6];
  const float* Wo = (const float*)d_in[7];
  float* out = (float*)d_out;

  char* ws = (char*)d_ws;
  const size_t SZ = (size_t)M_TOT * D_MODEL * 2; // 16 MiB per bf16 [8192,1024]
  u16* qb = (u16*)ws;            // cvt(q) -> Q GEMM; then Vp; then attn_out
  u16* kb = (u16*)(ws + SZ);     // cvt(k) -> K GEMM; then Kf
  u16* vb = (u16*)(ws + 2 * SZ); // cvt(v) -> V GEMM; then Vf
  u16* Qp = (u16*)(ws + 3 * SZ);
  u16* Kp = (u16*)(ws + 4 * SZ);
  u16* Wqt = (u16*)(ws + 5 * SZ);
  u16* Wkt = Wqt + 1024 * 1024;
  u16* Wvt = Wkt + 1024 * 1024;
  u16* Wot = Wvt + 1024 * 1024;
  float* Mb = (float*)(Wot + 1024 * 1024);
  // lifetime-disjoint aliases:
  u16* Vp = qb;       // qb dead after Q GEMM; Vp dead after vfrag
  u16* Kf = kb;       // kb dead after K GEMM
  u16* Vf = vb;       // vb dead after V GEMM
  u16* attn_out = qb; // Vp dead after vfrag

  int n4 = M_TOT * D_MODEL / 4;
  cvt_f32_bf16<<<n4 / 256, 256, 0, stream>>>(q, qb, n4);
  cvt_f32_bf16<<<n4 / 256, 256, 0, stream>>>(k, kb, n4);
  cvt_f32_bf16<<<n4 / 256, 256, 0, stream>>>(v, vb, n4);
  mask_bias<<<(B_ * N_ + 255) / 256, 256, 0, stream>>>(mask, Mb, B_ * N_);
  dim3 wg(32, 32);
  wtrans<<<wg, 256, 0, stream>>>(Wq, Wqt);
  wtrans<<<wg, 256, 0, stream>>>(Wk, Wkt);
  wtrans<<<wg, 256, 0, stream>>>(Wv, Wvt);
  wtrans<<<wg, 256, 0, stream>>>(Wo, Wot);
  dim3 gg(D_MODEL / 128, M_TOT / 128);
  gemm_bt<false><<<gg, 256, 0, stream>>>(qb, Wqt, nullptr, Qp, M_TOT, D_MODEL, D_MODEL);
  gemm_bt<false><<<gg, 256, 0, stream>>>(kb, Wkt, nullptr, Kp, M_TOT, D_MODEL, D_MODEL);
  gemm_bt<false><<<gg, 256, 0, stream>>>(vb, Wvt, nullptr, Vp, M_TOT, D_MODEL, D_MODEL);
  dim3 fg(N_ / 64, NHEAD, B_);
  kfrag_k<<<fg, 256, 0, stream>>>(Kp, Kf);
  vfrag_k<<<fg, 256, 0, stream>>>(Vp, Vf);
  attn_fwd<<<512, 256, 0, stream>>>(Qp, Kf, Vf, Mb, attn_out);
  gemm_bt<true><<<gg, 256, 0, stream>>>(attn_out, Wot, out, nullptr, M_TOT, D_MODEL, D_MODEL);
}